// Round 8
// baseline (1062.333 us; speedup 1.0000x reference)
//
#include <hip/hip_runtime.h>

#define BB 4
#define TT 2048
#define DD 1024
#define HH 16
#define DHH 64

using half8  = __attribute__((ext_vector_type(8))) _Float16;
using half4v = __attribute__((ext_vector_type(4))) _Float16;
using f32x4  = __attribute__((ext_vector_type(4))) float;

#define EXP2C 0.18033688011112042f  // log2(e)/8

__device__ __forceinline__ float fexp2(float x) {
#if __has_builtin(__builtin_amdgcn_exp2f)
  return __builtin_amdgcn_exp2f(x);
#else
  return exp2f(x);
#endif
}

__device__ __forceinline__ void gload_lds16(const _Float16* g, _Float16* l) {
  __builtin_amdgcn_global_load_lds((const __attribute__((address_space(1))) void*)g,
                                   (__attribute__((address_space(3))) void*)l, 16, 0, 0);
}

// ---------------- fused fp32 -> fp16 convert: x + 4 weights in one launch ----------------
__global__ void cvt_all(const float* __restrict__ x,
                        const float* __restrict__ wq, const float* __restrict__ wk,
                        const float* __restrict__ wv, const float* __restrict__ wo,
                        _Float16* __restrict__ xh,
                        _Float16* __restrict__ wqh, _Float16* __restrict__ wkh,
                        _Float16* __restrict__ wvh, _Float16* __restrict__ woh) {
  const float* s; _Float16* d; int n8, b0, nb;
  int b = blockIdx.x;
  if (b < 512) { s = x; d = xh; n8 = BB * TT * DD / 8; b0 = b; nb = 512; }
  else {
    int wsel = (b - 512) >> 6;
    b0 = (b - 512) & 63; nb = 64; n8 = DD * DD / 8;
    s = wsel == 0 ? wq : wsel == 1 ? wk : wsel == 2 ? wv : wo;
    d = wsel == 0 ? wqh : wsel == 1 ? wkh : wsel == 2 ? wvh : woh;
  }
  for (int i = b0 * 256 + threadIdx.x; i < n8; i += nb * 256) {
    const float4* p = (const float4*)(s + (size_t)i * 8);
    float4 a = p[0], bb = p[1];
    half8 h;
    h[0] = (_Float16)a.x; h[1] = (_Float16)a.y; h[2] = (_Float16)a.z; h[3] = (_Float16)a.w;
    h[4] = (_Float16)bb.x; h[5] = (_Float16)bb.y; h[6] = (_Float16)bb.z; h[7] = (_Float16)bb.w;
    *(half8*)(d + (size_t)i * 8) = h;
  }
}

// common staging macro (identifiers A, Bw, row0, col0, K, tid, As, Bs must exist)
#define GEMM_STAGE(K0, BSEL)                                                        \
  _Pragma("unroll") for (int it = 0; it < 4; ++it) {                                \
    int chunk = tid + it * 256;                                                     \
    int r = chunk >> 3, pb = chunk & 7, lb = pb ^ (r & 7);                          \
    gload_lds16(A + (size_t)(row0 + r) * K + (K0) * 64 + lb * 8, As[BSEL] + chunk * 8);  \
    gload_lds16(Bw + (size_t)(col0 + r) * K + (K0) * 64 + lb * 8, Bs[BSEL] + chunk * 8); \
  }

// ---------------- fused QKV NT GEMM: one launch, blockIdx.y selects weight ----------------
__global__ __launch_bounds__(256, 2) void gemm_qkv(const _Float16* __restrict__ A,
                                                   const _Float16* __restrict__ Wqh,
                                                   const _Float16* __restrict__ Wkh,
                                                   const _Float16* __restrict__ Wvh,
                                                   const float* __restrict__ bq,
                                                   const float* __restrict__ bk,
                                                   const float* __restrict__ bv,
                                                   _Float16* __restrict__ qh,
                                                   _Float16* __restrict__ kh,
                                                   _Float16* __restrict__ vTh) {
  constexpr int K = 1024;
  __shared__ _Float16 As[2][128 * 64];
  __shared__ _Float16 Bs[2][128 * 64];
  const int tid = threadIdx.x;
  const int l = tid & 63, w = tid >> 6;
  const int wm = w >> 1, wn = w & 1;
  const int lg = l >> 4, lr16 = l & 15;
  const int wsel = (int)blockIdx.y >> 3;
  const _Float16* Bw = wsel == 0 ? Wqh : wsel == 1 ? Wkh : Wvh;
  const float* bias = wsel == 0 ? bq : wsel == 1 ? bk : bv;
  const int row0 = blockIdx.x * 128, col0 = ((int)blockIdx.y & 7) * 128;

  f32x4 acc[4][4];
#pragma unroll
  for (int i = 0; i < 4; ++i)
#pragma unroll
    for (int j = 0; j < 4; ++j) acc[i][j] = (f32x4)0.0f;

  GEMM_STAGE(0, 0);
  int cur = 0;
  for (int k0 = 0; k0 < 16; ++k0) {
    __syncthreads();
    if (k0 < 15) GEMM_STAGE(k0 + 1, cur ^ 1);
#pragma unroll
    for (int kb = 0; kb < 2; ++kb) {
      half8 a[4], b[4];
#pragma unroll
      for (int f = 0; f < 4; ++f) {
        int ar = wm * 64 + f * 16 + lr16;
        a[f] = *(const half8*)(As[cur] + ar * 64 + ((kb * 4 + lg) ^ (ar & 7)) * 8);
        int br = wn * 64 + f * 16 + lr16;
        b[f] = *(const half8*)(Bs[cur] + br * 64 + ((kb * 4 + lg) ^ (br & 7)) * 8);
      }
#pragma unroll
      for (int i = 0; i < 4; ++i)
#pragma unroll
        for (int j = 0; j < 4; ++j)
          acc[i][j] = __builtin_amdgcn_mfma_f32_16x16x32_f16(a[i], b[j], acc[i][j], 0, 0, 0);
    }
    cur ^= 1;
  }

  // epilogue: C/D layout col=lane&15, row=(lane>>4)*4+reg  [m89-verified]
#pragma unroll
  for (int fi = 0; fi < 4; ++fi) {
#pragma unroll
    for (int fj = 0; fj < 4; ++fj) {
      int gi0 = row0 + wm * 64 + fi * 16 + lg * 4;
      int gj = col0 + wn * 64 + fj * 16 + lr16;
      float bj = bias[gj];
      int b = gi0 >> 11, t0 = gi0 & 2047;
      int h = gj >> 6, dh = gj & 63;
      if (wsel < 2) {
        _Float16* O = wsel ? kh : qh;
#pragma unroll
        for (int r = 0; r < 4; ++r)
          O[(((size_t)(b * HH + h) * TT + (t0 + r)) << 6) + dh] = (_Float16)(acc[fi][fj][r] + bj);
      } else {
        half4v tmp;
#pragma unroll
        for (int r = 0; r < 4; ++r) tmp[r] = (_Float16)(acc[fi][fj][r] + bj);
        *(half4v*)(vTh + (((size_t)(b * HH + h) * DHH + dh) * TT + t0)) = tmp;
      }
    }
  }
}

// ---------------- final NT GEMM: out[M=8192,N=1024] = zh @ Wo^T + bo (fp32) ----------------
__global__ __launch_bounds__(256, 2) void gemm_out(const _Float16* __restrict__ A,
                                                   const _Float16* __restrict__ Bw,
                                                   const float* __restrict__ bias,
                                                   float* __restrict__ Cout) {
  constexpr int K = 1024;
  __shared__ _Float16 As[2][128 * 64];
  __shared__ _Float16 Bs[2][128 * 64];
  const int tid = threadIdx.x;
  const int l = tid & 63, w = tid >> 6;
  const int wm = w >> 1, wn = w & 1;
  const int lg = l >> 4, lr16 = l & 15;
  const int row0 = blockIdx.x * 128, col0 = blockIdx.y * 128;

  f32x4 acc[4][4];
#pragma unroll
  for (int i = 0; i < 4; ++i)
#pragma unroll
    for (int j = 0; j < 4; ++j) acc[i][j] = (f32x4)0.0f;

  GEMM_STAGE(0, 0);
  int cur = 0;
  for (int k0 = 0; k0 < 16; ++k0) {
    __syncthreads();
    if (k0 < 15) GEMM_STAGE(k0 + 1, cur ^ 1);
#pragma unroll
    for (int kb = 0; kb < 2; ++kb) {
      half8 a[4], b[4];
#pragma unroll
      for (int f = 0; f < 4; ++f) {
        int ar = wm * 64 + f * 16 + lr16;
        a[f] = *(const half8*)(As[cur] + ar * 64 + ((kb * 4 + lg) ^ (ar & 7)) * 8);
        int br = wn * 64 + f * 16 + lr16;
        b[f] = *(const half8*)(Bs[cur] + br * 64 + ((kb * 4 + lg) ^ (br & 7)) * 8);
      }
#pragma unroll
      for (int i = 0; i < 4; ++i)
#pragma unroll
        for (int j = 0; j < 4; ++j)
          acc[i][j] = __builtin_amdgcn_mfma_f32_16x16x32_f16(a[i], b[j], acc[i][j], 0, 0, 0);
    }
    cur ^= 1;
  }

#pragma unroll
  for (int fi = 0; fi < 4; ++fi) {
#pragma unroll
    for (int fj = 0; fj < 4; ++fj) {
      int gi0 = row0 + wm * 64 + fi * 16 + lg * 4;
      int gj = col0 + wn * 64 + fj * 16 + lr16;
      float bj = bias[gj];
#pragma unroll
      for (int r = 0; r < 4; ++r)
        Cout[(size_t)(gi0 + r) * DD + gj] = acc[fi][fj][r] + bj;
    }
  }
}

// ---------------- fused attention: LDS-FREE, BARRIER-FREE, all-register -------------------
// 8 waves x 16 q-rows, each wave fully independent (no __syncthreads anywhere).
// K/V read DIRECTLY from global (L2/LLC-resident, perfect 128B line utilization:
// kh rows = 128 B; vT rows give exactly the 64 t-values of a tile per line).
// Sweep1: QK (S^T = mfma32(K,Q)) + exp + rowsum + PV direct from regs via mfma16
//   (ph is the PV A-frag: R7-hardware-verified chain). z stays in regs, unnormalized.
// Sweep2: QK + exp*inv -> dwordx4 A-stores, free-running against DRAM.
__global__ __launch_bounds__(512, 4) void attn_kernel(const _Float16* __restrict__ qh,
                                                      const _Float16* __restrict__ kh,
                                                      const _Float16* __restrict__ vTh,
                                                      const float* __restrict__ gates,
                                                      float* __restrict__ Aout,
                                                      _Float16* __restrict__ zh) {
  const int tid = threadIdx.x;
  const int l = tid & 63, w = tid >> 6;
  const int lg = l >> 4, lr16 = l & 15;
  const int wr0 = w * 16;
  const int blk = ((int)blockIdx.x & 7) * 128 + ((int)blockIdx.x >> 3);  // XCD chunk swizzle
  const int rt = blk & 15, bh = blk >> 4;
  const _Float16* Qp = qh + (size_t)bh * TT * DHH + (size_t)rt * 128 * DHH;
  const _Float16* Kp = kh + (size_t)bh * TT * DHH;
  const _Float16* Vp = vTh + (size_t)bh * DHH * TT;
  float* Ap = Aout + (size_t)bh * TT * TT + (size_t)rt * 128 * TT;
  const float gate = gates[bh];

  const int qrow = wr0 + lr16;  // this lane's q-row for QK/A (local in 128)
  const half8 aQ0 = *(const half8*)(Qp + (size_t)qrow * DHH + lg * 8);
  const half8 aQ1 = *(const half8*)(Qp + (size_t)qrow * DHH + (4 + lg) * 8);

  // -------- sweep 1: rowsums + PV (z unnormalized in regs) --------
  float rs = 0.f;
  f32x4 z[4];
#pragma unroll
  for (int j = 0; j < 4; ++j) z[j] = (f32x4)0.0f;

  for (int ct = 0; ct < 32; ++ct) {
    const _Float16* Kt = Kp + (size_t)ct * 64 * DHH;
    const _Float16* Vt = Vp + (size_t)ct * 64;  // V^T [dh][t], col block ct*64
    f32x4 s[4];
#pragma unroll
    for (int j = 0; j < 4; ++j) s[j] = (f32x4)0.0f;
#pragma unroll
    for (int kb = 0; kb < 2; ++kb) {
      half8 aQ = kb ? aQ1 : aQ0;
#pragma unroll
      for (int fc = 0; fc < 4; ++fc) {
        half8 bK = *(const half8*)(Kt + (size_t)(fc * 16 + lr16) * DHH + (kb * 4 + lg) * 8);
        s[fc] = __builtin_amdgcn_mfma_f32_16x16x32_f16(bK, aQ, s[fc], 0, 0, 0);  // S^T
      }
    }
#pragma unroll
    for (int fc = 0; fc < 4; ++fc) {
      half4v ph;
#pragma unroll
      for (int r = 0; r < 4; ++r) {
        float p = fexp2(s[fc][r] * EXP2C);
        rs += p;
        ph[r] = (_Float16)p;
      }
      // PV direct: ph = A-frag (q=lr16 row, k=lg*4+j of chunk fc); bV = B-frag
#pragma unroll
      for (int fcol = 0; fcol < 4; ++fcol) {
        half4v bV = *(const half4v*)(Vt + (size_t)(fcol * 16 + lr16) * TT + fc * 16 + lg * 4);
        z[fcol] = __builtin_amdgcn_mfma_f32_16x16x16f16(ph, bV, z[fcol], 0, 0, 0);
      }
    }
  }

  // rowsum reduce over the 4 lg-groups (lanes sharing lr16)
  rs += __shfl_xor(rs, 16, 64);
  rs += __shfl_xor(rs, 32, 64);
  const float inv = gate / rs;  // valid for q = qrow (lr16-indexed)
  // inv for the z-frag's q-mapping (q = lg*4 + r): pull from lanes lr16 = lg*4+r
  f32x4 inv4;
#pragma unroll
  for (int r = 0; r < 4; ++r) inv4[r] = __shfl(inv, lg * 4 + r, 64);

  // -------- sweep 2: A stores (free-running) --------
  for (int ct = 0; ct < 32; ++ct) {
    const _Float16* Kt = Kp + (size_t)ct * 64 * DHH;
    f32x4 s[4];
#pragma unroll
    for (int j = 0; j < 4; ++j) s[j] = (f32x4)0.0f;
#pragma unroll
    for (int kb = 0; kb < 2; ++kb) {
      half8 aQ = kb ? aQ1 : aQ0;
#pragma unroll
      for (int fc = 0; fc < 4; ++fc) {
        half8 bK = *(const half8*)(Kt + (size_t)(fc * 16 + lr16) * DHH + (kb * 4 + lg) * 8);
        s[fc] = __builtin_amdgcn_mfma_f32_16x16x32_f16(bK, aQ, s[fc], 0, 0, 0);  // S^T
      }
    }
#pragma unroll
    for (int fc = 0; fc < 4; ++fc) {
      f32x4 o;
#pragma unroll
      for (int r = 0; r < 4; ++r) o[r] = fexp2(s[fc][r] * EXP2C) * inv;
      *(f32x4*)(Ap + (size_t)qrow * TT + ct * 64 + fc * 16 + lg * 4) = o;
    }
  }

  // -------- z epilogue: z frag row q = wr0 + lg*4 + j, col dh = fcol*16 + lr16 --------
  const int b = bh >> 4, h = bh & 15;
#pragma unroll
  for (int fcol = 0; fcol < 4; ++fcol)
#pragma unroll
    for (int j = 0; j < 4; ++j) {
      int q = rt * 128 + wr0 + lg * 4 + j;
      zh[((size_t)(b * TT + q)) * DD + h * 64 + fcol * 16 + lr16] =
          (_Float16)(z[fcol][j] * inv4[j]);
    }
}

extern "C" void kernel_launch(void* const* d_in, const int* in_sizes, int n_in,
                              void* d_out, int out_size, void* d_ws, size_t ws_size,
                              hipStream_t stream) {
  const float* x     = (const float*)d_in[0];
  const float* gates = (const float*)d_in[1];
  const float* Wq    = (const float*)d_in[2];
  const float* bq    = (const float*)d_in[3];
  const float* Wk    = (const float*)d_in[4];
  const float* bk    = (const float*)d_in[5];
  const float* Wv    = (const float*)d_in[6];
  const float* bv    = (const float*)d_in[7];
  const float* Wo    = (const float*)d_in[8];
  const float* bo    = (const float*)d_in[9];

  float* out  = (float*)d_out;
  float* Aout = out + (size_t)BB * TT * DD;

  char* ws = (char*)d_ws;
  _Float16* xh  = (_Float16*)(ws);                       // 16 MB (reused as zh)
  _Float16* Wqh = (_Float16*)(ws + (16ull << 20));       // 2 MB
  _Float16* Wkh = (_Float16*)(ws + (18ull << 20));       // 2 MB
  _Float16* Wvh = (_Float16*)(ws + (20ull << 20));       // 2 MB
  _Float16* Woh = (_Float16*)(ws + (22ull << 20));       // 2 MB
  _Float16* qh  = (_Float16*)(ws + (24ull << 20));       // 16 MB
  _Float16* kh  = (_Float16*)(ws + (40ull << 20));       // 16 MB
  _Float16* vTh = (_Float16*)(ws + (56ull << 20));       // 16 MB
  _Float16* zh  = xh;  // x no longer needed once V-proj done

  cvt_all<<<768, 256, 0, stream>>>(x, Wq, Wk, Wv, Wo, xh, Wqh, Wkh, Wvh, Woh);

  gemm_qkv<<<dim3(BB * TT / 128, 24), 256, 0, stream>>>(xh, Wqh, Wkh, Wvh, bq, bk, bv,
                                                        qh, kh, vTh);

  attn_kernel<<<BB * HH * (TT / 128), 512, 0, stream>>>(qh, kh, vTh, gates, Aout, zh);

  gemm_out<<<dim3(BB * TT / 128, DD / 128), 256, 0, stream>>>(zh, Woh, bo, out);
}

// Round 9
// 452.207 us; speedup vs baseline: 2.3492x; 2.3492x over previous
//
#include <hip/hip_runtime.h>

#define BB 4
#define TT 2048
#define DD 1024
#define HH 16
#define DHH 64

using half8  = __attribute__((ext_vector_type(8))) _Float16;
using half4v = __attribute__((ext_vector_type(4))) _Float16;
using f32x4  = __attribute__((ext_vector_type(4))) float;

#define EXP2C 0.18033688011112042f  // log2(e)/8

__device__ __forceinline__ float fexp2(float x) {
#if __has_builtin(__builtin_amdgcn_exp2f)
  return __builtin_amdgcn_exp2f(x);
#else
  return exp2f(x);
#endif
}

__device__ __forceinline__ void gload_lds16(const _Float16* g, _Float16* l) {
  __builtin_amdgcn_global_load_lds((const __attribute__((address_space(1))) void*)g,
                                   (__attribute__((address_space(3))) void*)l, 16, 0, 0);
}

// ---------------- fused fp32 -> fp16 convert: x + 4 weights in one launch ----------------
__global__ void cvt_all(const float* __restrict__ x,
                        const float* __restrict__ wq, const float* __restrict__ wk,
                        const float* __restrict__ wv, const float* __restrict__ wo,
                        _Float16* __restrict__ xh,
                        _Float16* __restrict__ wqh, _Float16* __restrict__ wkh,
                        _Float16* __restrict__ wvh, _Float16* __restrict__ woh) {
  const float* s; _Float16* d; int n8, b0, nb;
  int b = blockIdx.x;
  if (b < 512) { s = x; d = xh; n8 = BB * TT * DD / 8; b0 = b; nb = 512; }
  else {
    int wsel = (b - 512) >> 6;
    b0 = (b - 512) & 63; nb = 64; n8 = DD * DD / 8;
    s = wsel == 0 ? wq : wsel == 1 ? wk : wsel == 2 ? wv : wo;
    d = wsel == 0 ? wqh : wsel == 1 ? wkh : wsel == 2 ? wvh : woh;
  }
  for (int i = b0 * 256 + threadIdx.x; i < n8; i += nb * 256) {
    const float4* p = (const float4*)(s + (size_t)i * 8);
    float4 a = p[0], bb = p[1];
    half8 h;
    h[0] = (_Float16)a.x; h[1] = (_Float16)a.y; h[2] = (_Float16)a.z; h[3] = (_Float16)a.w;
    h[4] = (_Float16)bb.x; h[5] = (_Float16)bb.y; h[6] = (_Float16)bb.z; h[7] = (_Float16)bb.w;
    *(half8*)(d + (size_t)i * 8) = h;
  }
}

// common staging macro (identifiers A, Bw, row0, col0, K, tid, As, Bs must exist)
#define GEMM_STAGE(K0, BSEL)                                                        \
  _Pragma("unroll") for (int it = 0; it < 4; ++it) {                                \
    int chunk = tid + it * 256;                                                     \
    int r = chunk >> 3, pb = chunk & 7, lb = pb ^ (r & 7);                          \
    gload_lds16(A + (size_t)(row0 + r) * K + (K0) * 64 + lb * 8, As[BSEL] + chunk * 8);  \
    gload_lds16(Bw + (size_t)(col0 + r) * K + (K0) * 64 + lb * 8, Bs[BSEL] + chunk * 8); \
  }

// ---------------- fused QKV NT GEMM: one launch, blockIdx.y selects weight ----------------
// y in [0,24): wsel = y>>3 (0=Q,1=K -> [B][H][T][DH] fp16; 2=V -> [B][H][DH][T] fp16)
__global__ __launch_bounds__(256, 2) void gemm_qkv(const _Float16* __restrict__ A,
                                                   const _Float16* __restrict__ Wqh,
                                                   const _Float16* __restrict__ Wkh,
                                                   const _Float16* __restrict__ Wvh,
                                                   const float* __restrict__ bq,
                                                   const float* __restrict__ bk,
                                                   const float* __restrict__ bv,
                                                   _Float16* __restrict__ qh,
                                                   _Float16* __restrict__ kh,
                                                   _Float16* __restrict__ vTh) {
  constexpr int K = 1024;
  __shared__ _Float16 As[2][128 * 64];
  __shared__ _Float16 Bs[2][128 * 64];
  const int tid = threadIdx.x;
  const int l = tid & 63, w = tid >> 6;
  const int wm = w >> 1, wn = w & 1;
  const int lg = l >> 4, lr16 = l & 15;
  const int wsel = (int)blockIdx.y >> 3;
  const _Float16* Bw = wsel == 0 ? Wqh : wsel == 1 ? Wkh : Wvh;
  const float* bias = wsel == 0 ? bq : wsel == 1 ? bk : bv;
  const int row0 = blockIdx.x * 128, col0 = ((int)blockIdx.y & 7) * 128;

  f32x4 acc[4][4];
#pragma unroll
  for (int i = 0; i < 4; ++i)
#pragma unroll
    for (int j = 0; j < 4; ++j) acc[i][j] = (f32x4)0.0f;

  GEMM_STAGE(0, 0);
  int cur = 0;
  for (int k0 = 0; k0 < 16; ++k0) {
    __syncthreads();
    if (k0 < 15) GEMM_STAGE(k0 + 1, cur ^ 1);
#pragma unroll
    for (int kb = 0; kb < 2; ++kb) {
      half8 a[4], b[4];
#pragma unroll
      for (int f = 0; f < 4; ++f) {
        int ar = wm * 64 + f * 16 + lr16;
        a[f] = *(const half8*)(As[cur] + ar * 64 + ((kb * 4 + lg) ^ (ar & 7)) * 8);
        int br = wn * 64 + f * 16 + lr16;
        b[f] = *(const half8*)(Bs[cur] + br * 64 + ((kb * 4 + lg) ^ (br & 7)) * 8);
      }
#pragma unroll
      for (int i = 0; i < 4; ++i)
#pragma unroll
        for (int j = 0; j < 4; ++j)
          acc[i][j] = __builtin_amdgcn_mfma_f32_16x16x32_f16(a[i], b[j], acc[i][j], 0, 0, 0);
    }
    cur ^= 1;
  }

  // epilogue: C/D layout col=lane&15, row=(lane>>4)*4+reg  [m89-verified]
#pragma unroll
  for (int fi = 0; fi < 4; ++fi) {
#pragma unroll
    for (int fj = 0; fj < 4; ++fj) {
      int gi0 = row0 + wm * 64 + fi * 16 + lg * 4;
      int gj = col0 + wn * 64 + fj * 16 + lr16;
      float bj = bias[gj];
      int b = gi0 >> 11, t0 = gi0 & 2047;
      int h = gj >> 6, dh = gj & 63;
      if (wsel < 2) {
        _Float16* O = wsel ? kh : qh;
#pragma unroll
        for (int r = 0; r < 4; ++r)
          O[(((size_t)(b * HH + h) * TT + (t0 + r)) << 6) + dh] = (_Float16)(acc[fi][fj][r] + bj);
      } else {
        half4v tmp;
#pragma unroll
        for (int r = 0; r < 4; ++r) tmp[r] = (_Float16)(acc[fi][fj][r] + bj);
        *(half4v*)(vTh + (((size_t)(b * HH + h) * DHH + dh) * TT + t0)) = tmp;
      }
    }
  }
}

// ---------------- final NT GEMM: out[M=8192,N=1024] = zh @ Wo^T + bo (fp32, nt store) -------
__global__ __launch_bounds__(256, 2) void gemm_out(const _Float16* __restrict__ A,
                                                   const _Float16* __restrict__ Bw,
                                                   const float* __restrict__ bias,
                                                   float* __restrict__ Cout) {
  constexpr int K = 1024;
  __shared__ _Float16 As[2][128 * 64];
  __shared__ _Float16 Bs[2][128 * 64];
  const int tid = threadIdx.x;
  const int l = tid & 63, w = tid >> 6;
  const int wm = w >> 1, wn = w & 1;
  const int lg = l >> 4, lr16 = l & 15;
  const int row0 = blockIdx.x * 128, col0 = blockIdx.y * 128;

  f32x4 acc[4][4];
#pragma unroll
  for (int i = 0; i < 4; ++i)
#pragma unroll
    for (int j = 0; j < 4; ++j) acc[i][j] = (f32x4)0.0f;

  GEMM_STAGE(0, 0);
  int cur = 0;
  for (int k0 = 0; k0 < 16; ++k0) {
    __syncthreads();
    if (k0 < 15) GEMM_STAGE(k0 + 1, cur ^ 1);
#pragma unroll
    for (int kb = 0; kb < 2; ++kb) {
      half8 a[4], b[4];
#pragma unroll
      for (int f = 0; f < 4; ++f) {
        int ar = wm * 64 + f * 16 + lr16;
        a[f] = *(const half8*)(As[cur] + ar * 64 + ((kb * 4 + lg) ^ (ar & 7)) * 8);
        int br = wn * 64 + f * 16 + lr16;
        b[f] = *(const half8*)(Bs[cur] + br * 64 + ((kb * 4 + lg) ^ (br & 7)) * 8);
      }
#pragma unroll
      for (int i = 0; i < 4; ++i)
#pragma unroll
        for (int j = 0; j < 4; ++j)
          acc[i][j] = __builtin_amdgcn_mfma_f32_16x16x32_f16(a[i], b[j], acc[i][j], 0, 0, 0);
    }
    cur ^= 1;
  }

#pragma unroll
  for (int fi = 0; fi < 4; ++fi) {
#pragma unroll
    for (int fj = 0; fj < 4; ++fj) {
      int gi0 = row0 + wm * 64 + fi * 16 + lg * 4;
      int gj = col0 + wn * 64 + fj * 16 + lr16;
      float bj = bias[gj];
#pragma unroll
      for (int r = 0; r < 4; ++r)
        __builtin_nontemporal_store(acc[fi][fj][r] + bj, &Cout[(size_t)(gi0 + r) * DD + gj]);
    }
  }
}

// ---------------- fused attention (best-measured variant, R1: 454.4 us) ----------------
// 512 threads = 8 waves x 16 q-rows. Double-buffered K/V via global_load_lds.
// Sweep1: lane-local exp partials (reduce once at end).
// Sweep2: recompute scores, A = gate*exp2(s*C)/sum -> nontemporal fp32 store + Ps fp16 -> PV.
// Sweep2 barriers are raw s_barrier + counted vmcnt(8): the 2 staging loads are the oldest
// outstanding vmem ops (pinned by sched_barrier), so A-stores keep draining across tiles.
__global__ __launch_bounds__(512, 2) void attn_kernel(const _Float16* __restrict__ qh,
                                                      const _Float16* __restrict__ kh,
                                                      const _Float16* __restrict__ vTh,
                                                      const float* __restrict__ gates,
                                                      float* __restrict__ Aout,
                                                      _Float16* __restrict__ zh) {
  __shared__ _Float16 Qs[128 * 64];
  __shared__ _Float16 Ks[2][64 * 64];
  __shared__ _Float16 Vs[2][64 * 64];
  __shared__ _Float16 Ps[128 * 64];
  const int tid = threadIdx.x;
  const int l = tid & 63, w = tid >> 6;
  const int lg = l >> 4, lr16 = l & 15;
  const int wr0 = w * 16;
  const int blk = ((int)blockIdx.x & 7) * 128 + ((int)blockIdx.x >> 3);  // XCD chunk swizzle
  const int rt = blk & 15, bh = blk >> 4;
  const _Float16* Qp = qh + (size_t)bh * TT * DHH + (size_t)rt * 128 * DHH;
  const _Float16* Kp = kh + (size_t)bh * TT * DHH;
  const _Float16* Vp = vTh + (size_t)bh * DHH * TT;
  float* Ap = Aout + (size_t)bh * TT * TT + (size_t)rt * 128 * TT;
  const float gate = gates[bh];

  // Q tile [128][64] staged via global_load_lds, source pre-swizzled
#pragma unroll
  for (int it = 0; it < 2; ++it) {
    int chunk = tid + it * 512;
    int r = chunk >> 3, pb = chunk & 7, lb = pb ^ (r & 7);
    gload_lds16(Qp + (size_t)r * DHH + lb * 8, Qs + chunk * 8);
  }

#define STAGE_K(CT, BSEL) {                                                   \
    int chunk = tid; int r = chunk >> 3, pb = chunk & 7, lb = pb ^ (r & 7);   \
    gload_lds16(Kp + (size_t)((CT) * 64 + r) * DHH + lb * 8, Ks[BSEL] + chunk * 8); }
#define STAGE_V(CT, BSEL) {                                                   \
    int chunk = tid; int r = chunk >> 3, pb = chunk & 7, lb = pb ^ (r & 7);   \
    gload_lds16(Vp + (size_t)r * TT + (CT) * 64 + lb * 8, Vs[BSEL] + chunk * 8); }

  // -------- sweep 1: row sums (lane-local partials) --------
  STAGE_K(0, 0);
  float rs[4] = {0.f, 0.f, 0.f, 0.f};
  int cur = 0;
  for (int ct = 0; ct < 32; ++ct) {
    __syncthreads();
    if (ct < 31) STAGE_K(ct + 1, cur ^ 1);
    f32x4 s[4];
#pragma unroll
    for (int j = 0; j < 4; ++j) s[j] = (f32x4)0.0f;
    __builtin_amdgcn_s_setprio(1);
#pragma unroll
    for (int kb = 0; kb < 2; ++kb) {
      int qr = wr0 + lr16;
      half8 aQ = *(const half8*)(Qs + qr * 64 + (((kb * 4 + lg) ^ (qr & 7)) * 8));
      half8 bK[4];
#pragma unroll
      for (int fc = 0; fc < 4; ++fc) {
        int kr = fc * 16 + lr16;
        bK[fc] = *(const half8*)(Ks[cur] + kr * 64 + (((kb * 4 + lg) ^ (kr & 7)) * 8));
      }
#pragma unroll
      for (int fc = 0; fc < 4; ++fc)
        s[fc] = __builtin_amdgcn_mfma_f32_16x16x32_f16(aQ, bK[fc], s[fc], 0, 0, 0);
    }
    __builtin_amdgcn_s_setprio(0);
#pragma unroll
    for (int fc = 0; fc < 4; ++fc)
#pragma unroll
      for (int r = 0; r < 4; ++r) rs[r] += fexp2(s[fc][r] * EXP2C);
    cur ^= 1;
  }

  // reduce across the 16 column-lanes (lr16), once
  float inv[4];
#pragma unroll
  for (int r = 0; r < 4; ++r) {
    float v = rs[r];
    v += __shfl_xor(v, 1, 64);
    v += __shfl_xor(v, 2, 64);
    v += __shfl_xor(v, 4, 64);
    v += __shfl_xor(v, 8, 64);
    inv[r] = gate / v;
  }

  // -------- sweep 2: A write + PV --------
  f32x4 z[4];
#pragma unroll
  for (int j = 0; j < 4; ++j) z[j] = (f32x4)0.0f;
  STAGE_K(0, 0);
  STAGE_V(0, 0);
  asm volatile("s_waitcnt vmcnt(0)\n\ts_barrier" ::: "memory");
  cur = 0;
  for (int ct = 0; ct < 32; ++ct) {
    if (ct < 31) {
      STAGE_K(ct + 1, cur ^ 1);
      STAGE_V(ct + 1, cur ^ 1);
    }
    __builtin_amdgcn_sched_barrier(0);  // keep staging loads oldest in the vmem queue
    f32x4 s[4];
#pragma unroll
    for (int j = 0; j < 4; ++j) s[j] = (f32x4)0.0f;
    __builtin_amdgcn_s_setprio(1);
#pragma unroll
    for (int kb = 0; kb < 2; ++kb) {
      int qr = wr0 + lr16;
      half8 aQ = *(const half8*)(Qs + qr * 64 + (((kb * 4 + lg) ^ (qr & 7)) * 8));
      half8 bK[4];
#pragma unroll
      for (int fc = 0; fc < 4; ++fc) {
        int kr = fc * 16 + lr16;
        bK[fc] = *(const half8*)(Ks[cur] + kr * 64 + (((kb * 4 + lg) ^ (kr & 7)) * 8));
      }
#pragma unroll
      for (int fc = 0; fc < 4; ++fc)
        s[fc] = __builtin_amdgcn_mfma_f32_16x16x32_f16(aQ, bK[fc], s[fc], 0, 0, 0);
    }
    __builtin_amdgcn_s_setprio(0);
    // A = gate * exp2(s*C) / rowsum -> global fp32 (nontemporal) + Ps fp16 (swizzled)
    const int rbase = wr0 + lg * 4;
#pragma unroll
    for (int fc = 0; fc < 4; ++fc) {
      int lc = fc * 16 + lr16;
#pragma unroll
      for (int r = 0; r < 4; ++r) {
        float av = fexp2(s[fc][r] * EXP2C) * inv[r];
        int lr = rbase + r;
        __builtin_nontemporal_store(av, &Ap[(size_t)lr * TT + (ct * 64 + lc)]);
        Ps[lr * 64 + (((fc * 2 + (lr16 >> 3)) ^ (lr & 7)) * 8) + (l & 7)] = (_Float16)av;
      }
    }
    // PV: z[t,d] += P[t,s] * V[s,d]  (Vs holds V^T tile [d][s]; same-wave LDS RAW, in-order DS)
    __builtin_amdgcn_s_setprio(1);
#pragma unroll
    for (int kb = 0; kb < 2; ++kb) {
      int pr = wr0 + lr16;
      half8 aP = *(const half8*)(Ps + pr * 64 + (((kb * 4 + lg) ^ (pr & 7)) * 8));
      half8 bV[4];
#pragma unroll
      for (int fc = 0; fc < 4; ++fc) {
        int vr = fc * 16 + lr16;
        bV[fc] = *(const half8*)(Vs[cur] + vr * 64 + (((kb * 4 + lg) ^ (vr & 7)) * 8));
      }
#pragma unroll
      for (int fc = 0; fc < 4; ++fc)
        z[fc] = __builtin_amdgcn_mfma_f32_16x16x32_f16(aP, bV[fc], z[fc], 0, 0, 0);
    }
    __builtin_amdgcn_s_setprio(0);
    if (ct < 31) {
      // counted barrier: wait only for the 2 staging loads (oldest); A-stores stay in flight
      asm volatile("s_waitcnt vmcnt(8) lgkmcnt(0)\n\ts_barrier" ::: "memory");
    }
    cur ^= 1;
  }

  // write z tile to zh [8192][1024] fp16
  const int b = bh >> 4, h = bh & 15;
  _Float16* zp = zh + ((size_t)b * TT + (size_t)rt * 128) * DD + h * 64;
  const int rbase = wr0 + lg * 4;
#pragma unroll
  for (int fc = 0; fc < 4; ++fc) {
    int d = fc * 16 + lr16;
#pragma unroll
    for (int r = 0; r < 4; ++r) zp[(size_t)(rbase + r) * DD + d] = (_Float16)z[fc][r];
  }
}

extern "C" void kernel_launch(void* const* d_in, const int* in_sizes, int n_in,
                              void* d_out, int out_size, void* d_ws, size_t ws_size,
                              hipStream_t stream) {
  const float* x     = (const float*)d_in[0];
  const float* gates = (const float*)d_in[1];
  const float* Wq    = (const float*)d_in[2];
  const float* bq    = (const float*)d_in[3];
  const float* Wk    = (const float*)d_in[4];
  const float* bk    = (const float*)d_in[5];
  const float* Wv    = (const float*)d_in[6];
  const float* bv    = (const float*)d_in[7];
  const float* Wo    = (const float*)d_in[8];
  const float* bo    = (const float*)d_in[9];

  float* out  = (float*)d_out;
  float* Aout = out + (size_t)BB * TT * DD;

  char* ws = (char*)d_ws;
  _Float16* xh  = (_Float16*)(ws);                       // 16 MB (reused as zh)
  _Float16* Wqh = (_Float16*)(ws + (16ull << 20));       // 2 MB
  _Float16* Wkh = (_Float16*)(ws + (18ull << 20));       // 2 MB
  _Float16* Wvh = (_Float16*)(ws + (20ull << 20));       // 2 MB
  _Float16* Woh = (_Float16*)(ws + (22ull << 20));       // 2 MB
  _Float16* qh  = (_Float16*)(ws + (24ull << 20));       // 16 MB
  _Float16* kh  = (_Float16*)(ws + (40ull << 20));       // 16 MB
  _Float16* vTh = (_Float16*)(ws + (56ull << 20));       // 16 MB
  _Float16* zh  = xh;  // x no longer needed once V-proj done

  cvt_all<<<768, 256, 0, stream>>>(x, Wq, Wk, Wv, Wo, xh, Wqh, Wkh, Wvh, Woh);

  gemm_qkv<<<dim3(BB * TT / 128, 24), 256, 0, stream>>>(xh, Wqh, Wkh, Wvh, bq, bk, bv,
                                                        qh, kh, vTh);

  attn_kernel<<<BB * HH * (TT / 128), 512, 0, stream>>>(qh, kh, vTh, gates, Aout, zh);

  gemm_out<<<dim3(BB * TT / 128, DD / 128), 256, 0, stream>>>(zh, Woh, bo, out);
}